// Round 5
// baseline (14422.668 us; speedup 1.0000x reference)
//
#include <hip/hip_runtime.h>
#include <hip/hip_bf16.h>

#define T_STEPS 4096
#define HID 2048
#define EMB 512
#define NCH 256

typedef unsigned long long u64;
typedef unsigned int u32;

__device__ __forceinline__ float sigm_f(float x) {
    x = fminf(fmaxf(x, -30.f), 30.f);
    return 1.f / (1.f + __expf(-x));
}
__device__ __forceinline__ float tanh_f(float x) {
    float ax = fminf(fabsf(x), 15.f);
    float e = __expf(2.f * ax);
    float t = (e - 1.f) / (e + 1.f);
    return copysignf(t, x);
}

// A1: per-char input projection P[c][j][g] = b_g[j] + emb[c]·Wg[0:512][j]
__global__ __launch_bounds__(256) void a1_proj(
    const float* __restrict__ emb,
    const float* __restrict__ Wf, const float* __restrict__ bf,
    const float* __restrict__ Wi, const float* __restrict__ bi,
    const float* __restrict__ Wo, const float* __restrict__ bo,
    const float* __restrict__ Wc, const float* __restrict__ bc,
    float* __restrict__ P) {
    const int g = blockIdx.x & 3;
    const int c0 = (blockIdx.x >> 2) << 3;
    const float* W = (g == 0) ? Wf : (g == 1) ? Wi : (g == 2) ? Wo : Wc;
    const float* b = (g == 0) ? bf : (g == 1) ? bi : (g == 2) ? bo : bc;
    __shared__ float el[8][EMB];
    const int tid = threadIdx.x;
    for (int q = tid; q < 8 * EMB; q += 256)
        el[q >> 9][q & 511] = emb[(size_t)(c0 + (q >> 9)) * EMB + (q & 511)];
    __syncthreads();
    float acc[8][8];
#pragma unroll
    for (int cc = 0; cc < 8; ++cc)
#pragma unroll
        for (int k = 0; k < 8; ++k) acc[cc][k] = 0.f;
    for (int e = 0; e < EMB; ++e) {
        float w8[8];
#pragma unroll
        for (int k = 0; k < 8; ++k) w8[k] = W[(size_t)e * HID + tid + (k << 8)];
#pragma unroll
        for (int cc = 0; cc < 8; ++cc) {
            float xe = el[cc][e];
#pragma unroll
            for (int k = 0; k < 8; ++k) acc[cc][k] = fmaf(xe, w8[k], acc[cc][k]);
        }
    }
    float bb[8];
#pragma unroll
    for (int k = 0; k < 8; ++k) bb[k] = b[tid + (k << 8)];
#pragma unroll
    for (int cc = 0; cc < 8; ++cc)
#pragma unroll
        for (int k = 0; k < 8; ++k)
            P[((((size_t)(c0 + cc) << 11) + tid + (k << 8)) << 2) + g] = acc[cc][k] + bb[k];
}

// A2: transpose recurrent weights -> WT[g][j][k] (k contiguous)
__global__ void a2_transpose(const float* __restrict__ Wf, const float* __restrict__ Wi,
                             const float* __restrict__ Wo, const float* __restrict__ Wc,
                             float* __restrict__ WT) {
    __shared__ float tile[32][33];
    const int g = blockIdx.z;
    const float* W = (g == 0) ? Wf : (g == 1) ? Wi : (g == 2) ? Wo : Wc;
    const int k0 = blockIdx.x << 5, j0 = blockIdx.y << 5;
    const int tx = threadIdx.x, ty = threadIdx.y;
#pragma unroll
    for (int i = 0; i < 32; i += 8)
        tile[ty + i][tx] = W[(size_t)(EMB + k0 + ty + i) * HID + j0 + tx];
    __syncthreads();
#pragma unroll
    for (int i = 0; i < 32; i += 8)
        WT[(((size_t)g * HID + j0 + ty + i) << 11) + k0 + tx] = tile[tx][ty + i];
}

// A3: init 2-slot mailbox. Slot 0 = h0 with tag 0; slot 1 poisoned with tag
// 0xFFFFFFFF (never equals any step id 0..4096).
__global__ void a3_init(const float* __restrict__ hidden, u64* __restrict__ hbuf, int ring) {
    int j = blockIdx.x * 256 + threadIdx.x;
    int total = ring << 11;
    if (j < total)
        hbuf[j] = (j < HID) ? (u64)__float_as_uint(hidden[j]) : 0xFFFFFFFF00000000ull;
}

// no-return 64b atomic swap, system scope (sc1): executes AT the coherence
// point -> the published value is observable the moment the atomic commits,
// independent of the writer's L2 write-through drain.
__device__ __forceinline__ void pub_swap(u64* p, u64 v) {
    asm volatile("global_atomic_swap_x2 %0, %1, off sc1" ::"v"(p), "v"(v) : "memory");
}

// B: persistent recurrence. 256 WGs x 512 threads, weights register-resident.
// Exchange: tagged u64 (tag<<32|f32) mailbox, 2 slots.
// R12 evidence recap: FOUR read-side strategies (stale-L2 spin / deep ring /
// MALL-direct sc0sc1 / leader-wave) all land ~11ms +-5%, and R3's FETCH ==
// R1's FETCH -> when the value becomes fetchable is write-side-limited: the
// relaxed system store drains lazily (~4000cy) from the writer's L2/write
// queue. R12 change (THE change): PUBLISH VIA NO-RETURN global_atomic_swap_x2
// sc1 -- atomics execute at the coherence point, committing immediately --
// and publish PER-WAVE the moment each wave's h is ready (lane 0 of each
// wave, 8 independent 8B atomics; no line-ownership ping-pong since atomics
// don't pull the line into L2). This also removes the LDS-gather + barrier +
// single-publisher serialization from the critical path. Readers: R3's
// all-thread sc0sc1 MALL-direct poll (R4's phase-split regressed: its sc0
// phase-2 read stale L2 lines that sc1 phase-1 never refilled).
__global__ __launch_bounds__(512, 2) void b_lstm(
    const int* __restrict__ seq, const float* __restrict__ cell,
    const float* __restrict__ P, const float* __restrict__ WT,
    u64* __restrict__ hbuf, float* __restrict__ hs, float* __restrict__ dout,
    int rmask) {
    __shared__ float h_lds[HID];
    __shared__ int seq_lds[T_STEPS];
    __shared__ float h_pub[8];
    // Occupancy pin: 89KB static LDS -> exactly 1 block/CU (proven neutral,
    // kept to hold the packing variable fixed across experiments).
    __shared__ float pad_force[16000];
    const int tid = threadIdx.x;
    const int l = tid & 63;
    const int jl = tid >> 6;
    const int jglob = (blockIdx.x << 3) + jl;

    ((volatile float*)pad_force)[tid] = 0.f;

    for (int q = tid; q < T_STEPS; q += 512) seq_lds[q] = seq[q];

    // per-thread k-ownership: k = q*256 + 4*l + r  (q=0..7, r=0..3)
    float4 wreg[4][8];
#pragma unroll
    for (int g = 0; g < 4; ++g)
#pragma unroll
        for (int q = 0; q < 8; ++q)
            wreg[g][q] = *(const float4*)&WT[(((size_t)g * HID + jglob) << 11) + (q << 8) + (l << 2)];

    float c_reg = cell[jglob];
    float h_last = 0.f;
    __syncthreads();

    for (int s = 0; s < T_STEPS; ++s) {
        // hs trace for step s-1 (h_pub gathered at the end barrier of iter
        // s-1) -- off the critical path.
        if (s > 0 && tid < 8) {
            hs[((size_t)(s - 1) << 11) + (blockIdx.x << 3) + tid] = h_pub[tid];
        }

        const int ch = seq_lds[s];
        const float4 xg = *(const float4*)(P + ((((size_t)ch << 11) + jglob) << 2));

        // stage h_s (tag==s) into LDS; thread tid owns h[tid+512m], m=0..3.
        // MALL-direct polls (sc0 sc1); per-u64 tags tolerate the staggered
        // per-wave atomic publishes.
        const u64* src = hbuf + ((size_t)(s & rmask) << 11);
        const u64* p0 = src + tid;
        const u64* p1 = p0 + 512;
        const u64* p2 = p0 + 1024;
        const u64* p3 = p0 + 1536;
        const u32 target = (u32)s;
        for (;;) {
            u64 t0, t1, t2, t3;
            asm volatile(
                "global_load_dwordx2 %0, %4, off sc0 sc1\n\t"
                "global_load_dwordx2 %1, %5, off sc0 sc1\n\t"
                "global_load_dwordx2 %2, %6, off sc0 sc1\n\t"
                "global_load_dwordx2 %3, %7, off sc0 sc1\n\t"
                "s_waitcnt vmcnt(0)"
                : "=&v"(t0), "=&v"(t1), "=&v"(t2), "=&v"(t3)
                : "v"(p0), "v"(p1), "v"(p2), "v"(p3)
                : "memory");
            u32 bad = ((u32)(t0 >> 32) ^ target) | ((u32)(t1 >> 32) ^ target) |
                      ((u32)(t2 >> 32) ^ target) | ((u32)(t3 >> 32) ^ target);
            if (bad == 0) {
                h_lds[tid]        = __uint_as_float((u32)t0);
                h_lds[512 + tid]  = __uint_as_float((u32)t1);
                h_lds[1024 + tid] = __uint_as_float((u32)t2);
                h_lds[1536 + tid] = __uint_as_float((u32)t3);
                break;
            }
        }
        __syncthreads();

        float a0 = 0.f, a1 = 0.f, a2 = 0.f, a3 = 0.f;
#pragma unroll
        for (int q = 0; q < 8; ++q) {
            const float4 hv = *(const float4*)&h_lds[(q << 8) + (l << 2)];
            a0 = fmaf(wreg[0][q].x, hv.x, a0);
            a0 = fmaf(wreg[0][q].y, hv.y, a0);
            a0 = fmaf(wreg[0][q].z, hv.z, a0);
            a0 = fmaf(wreg[0][q].w, hv.w, a0);
            a1 = fmaf(wreg[1][q].x, hv.x, a1);
            a1 = fmaf(wreg[1][q].y, hv.y, a1);
            a1 = fmaf(wreg[1][q].z, hv.z, a1);
            a1 = fmaf(wreg[1][q].w, hv.w, a1);
            a2 = fmaf(wreg[2][q].x, hv.x, a2);
            a2 = fmaf(wreg[2][q].y, hv.y, a2);
            a2 = fmaf(wreg[2][q].z, hv.z, a2);
            a2 = fmaf(wreg[2][q].w, hv.w, a2);
            a3 = fmaf(wreg[3][q].x, hv.x, a3);
            a3 = fmaf(wreg[3][q].y, hv.y, a3);
            a3 = fmaf(wreg[3][q].z, hv.z, a3);
            a3 = fmaf(wreg[3][q].w, hv.w, a3);
        }
        // 4-gate quadrant butterfly: fold ^32 (4 gates), split gates across
        // half-waves, fold ^16, split across quadrants, finish ^8..^1.
        a0 += __shfl_xor(a0, 32, 64);
        a1 += __shfl_xor(a1, 32, 64);
        a2 += __shfl_xor(a2, 32, 64);
        a3 += __shfl_xor(a3, 32, 64);
        float u0 = (l < 32) ? a0 : a2;
        float u1 = (l < 32) ? a1 : a3;
        u0 += __shfl_xor(u0, 16, 64);
        u1 += __shfl_xor(u1, 16, 64);
        float w = ((l & 16) == 0) ? u0 : u1;
        w += __shfl_xor(w, 8, 64);
        w += __shfl_xor(w, 4, 64);
        w += __shfl_xor(w, 2, 64);
        w += __shfl_xor(w, 1, 64);
        const float sf = __shfl(w, 0, 64);   // gate f sum
        const float si = __shfl(w, 16, 64);  // gate i sum
        const float so = __shfl(w, 32, 64);  // gate o sum
        const float sg = __shfl(w, 48, 64);  // gate g sum

        const float pf = sf + xg.x, pi = si + xg.y, po = so + xg.z, pg = sg + xg.w;
        const float f = sigm_f(pf);
        const float ii = sigm_f(pi);
        const float oo = sigm_f(po);
        const float gg = tanh_f(pg);
        c_reg = fmaf(f, c_reg, ii * gg);
        h_last = oo * tanh_f(c_reg);   // identical in every lane (broadcast sums)

        // PUBLISH IMMEDIATELY, per wave: tag s+1 into slot (s+1)&rmask.
        // Atomic commits at the MALL; readers' sc0sc1 polls see it without
        // waiting on any L2 write-through drain. Max inter-block skew is 1
        // step, so the overwritten slot (tag s-1) is dead for all blocks.
        if (l == 0) {
            u64 pv = ((u64)(u32)(s + 1) << 32) | (u64)__float_as_uint(h_last);
            pub_swap(hbuf + ((size_t)((s + 1) & rmask) << 11) + jglob, pv);
            h_pub[jl] = h_last;   // trace gather only (hs write next iter)
        }
        __syncthreads();          // h_lds reuse + h_pub ordering
    }
    // final: hs[T-1] trace + finals
    if (tid < 8) {
        hs[((size_t)(T_STEPS - 1) << 11) + (blockIdx.x << 3) + tid] = h_pub[tid];
    }
    if (l == 0) {
        dout[(size_t)T_STEPS * NCH + jglob] = h_last;          // h_fin
        dout[(size_t)T_STEPS * NCH + HID + jglob] = c_reg;     // c_fin
    }
}

// C: out[t] = hs[t] @ Wout + bout. grid 256 (16 t per block), 256 threads.
__global__ __launch_bounds__(256) void c_out(
    const float* __restrict__ hs, const float* __restrict__ Wout,
    const float* __restrict__ bout, float* __restrict__ out) {
    __shared__ float hsl[16][NCH];
    const int tid = threadIdx.x;
    const int bt = blockIdx.x << 4;
    float acc[16];
#pragma unroll
    for (int q = 0; q < 16; ++q) acc[q] = 0.f;
    for (int kc = 0; kc < 8; ++kc) {
#pragma unroll
        for (int q = 0; q < 16; ++q)
            hsl[q][tid] = hs[(((size_t)(bt + q)) << 11) + (kc << 8) + tid];
        __syncthreads();
        for (int kk = 0; kk < 256; ++kk) {
            float w = Wout[(size_t)((kc << 8) + kk) * NCH + tid];
#pragma unroll
            for (int q = 0; q < 16; ++q) acc[q] = fmaf(hsl[q][kk], w, acc[q]);
        }
        __syncthreads();
    }
    const float bb = bout[tid];
#pragma unroll
    for (int q = 0; q < 16; ++q) out[(size_t)(bt + q) * NCH + tid] = acc[q] + bb;
}

extern "C" void kernel_launch(void* const* d_in, const int* in_sizes, int n_in,
                              void* d_out, int out_size, void* d_ws, size_t ws_size,
                              hipStream_t stream) {
    const int* seq = (const int*)d_in[0];
    const float* hidden = (const float*)d_in[1];
    const float* cell = (const float*)d_in[2];
    const float* emb = (const float*)d_in[3];
    const float* Wf = (const float*)d_in[4];
    const float* bf = (const float*)d_in[5];
    const float* Wi = (const float*)d_in[6];
    const float* bi = (const float*)d_in[7];
    const float* Wo = (const float*)d_in[8];
    const float* bo = (const float*)d_in[9];
    const float* Wc = (const float*)d_in[10];
    const float* bc = (const float*)d_in[11];
    const float* Wout = (const float*)d_in[12];
    const float* bout = (const float*)d_in[13];
    float* out = (float*)d_out;

    // ws layout (floats): hbuf(2 slots x 2048 u64 = 8192 f) | WT(16.78M) |
    // P(2.10M) | hs(8.39M)
    float* wsf = (float*)d_ws;
    u64* hbuf = (u64*)d_ws;
    float* WT = wsf + 8192;
    float* P = WT + (size_t)4 * HID * HID;
    float* hs = P + (size_t)NCH * HID * 4;

    a1_proj<<<128, 256, 0, stream>>>(emb, Wf, bf, Wi, bi, Wo, bo, Wc, bc, P);
    a2_transpose<<<dim3(64, 64, 4), dim3(32, 8), 0, stream>>>(Wf, Wi, Wo, Wc, WT);
    a3_init<<<17, 256, 0, stream>>>(hidden, hbuf, 2);
    b_lstm<<<256, 512, 0, stream>>>(seq, cell, P, WT, hbuf, hs, out, 1);
    c_out<<<256, 256, 0, stream>>>(hs, Wout, bout, out);
}

// Round 6
// 12390.986 us; speedup vs baseline: 1.1640x; 1.1640x over previous
//
#include <hip/hip_runtime.h>
#include <hip/hip_bf16.h>

#define T_STEPS 4096
#define HID 2048
#define EMB 512
#define NCH 256

typedef unsigned long long u64;
typedef unsigned int u32;

__device__ __forceinline__ float sigm_f(float x) {
    x = fminf(fmaxf(x, -30.f), 30.f);
    return 1.f / (1.f + __expf(-x));
}
__device__ __forceinline__ float tanh_f(float x) {
    float ax = fminf(fabsf(x), 15.f);
    float e = __expf(2.f * ax);
    float t = (e - 1.f) / (e + 1.f);
    return copysignf(t, x);
}

// A1: per-char input projection P[c][j][g] = b_g[j] + emb[c]·Wg[0:512][j]
__global__ __launch_bounds__(256) void a1_proj(
    const float* __restrict__ emb,
    const float* __restrict__ Wf, const float* __restrict__ bf,
    const float* __restrict__ Wi, const float* __restrict__ bi,
    const float* __restrict__ Wo, const float* __restrict__ bo,
    const float* __restrict__ Wc, const float* __restrict__ bc,
    float* __restrict__ P) {
    const int g = blockIdx.x & 3;
    const int c0 = (blockIdx.x >> 2) << 3;
    const float* W = (g == 0) ? Wf : (g == 1) ? Wi : (g == 2) ? Wo : Wc;
    const float* b = (g == 0) ? bf : (g == 1) ? bi : (g == 2) ? bo : bc;
    __shared__ float el[8][EMB];
    const int tid = threadIdx.x;
    for (int q = tid; q < 8 * EMB; q += 256)
        el[q >> 9][q & 511] = emb[(size_t)(c0 + (q >> 9)) * EMB + (q & 511)];
    __syncthreads();
    float acc[8][8];
#pragma unroll
    for (int cc = 0; cc < 8; ++cc)
#pragma unroll
        for (int k = 0; k < 8; ++k) acc[cc][k] = 0.f;
    for (int e = 0; e < EMB; ++e) {
        float w8[8];
#pragma unroll
        for (int k = 0; k < 8; ++k) w8[k] = W[(size_t)e * HID + tid + (k << 8)];
#pragma unroll
        for (int cc = 0; cc < 8; ++cc) {
            float xe = el[cc][e];
#pragma unroll
            for (int k = 0; k < 8; ++k) acc[cc][k] = fmaf(xe, w8[k], acc[cc][k]);
        }
    }
    float bb[8];
#pragma unroll
    for (int k = 0; k < 8; ++k) bb[k] = b[tid + (k << 8)];
#pragma unroll
    for (int cc = 0; cc < 8; ++cc)
#pragma unroll
        for (int k = 0; k < 8; ++k)
            P[((((size_t)(c0 + cc) << 11) + tid + (k << 8)) << 2) + g] = acc[cc][k] + bb[k];
}

// A2: transpose recurrent weights -> WT[g][j][k] (k contiguous)
__global__ void a2_transpose(const float* __restrict__ Wf, const float* __restrict__ Wi,
                             const float* __restrict__ Wo, const float* __restrict__ Wc,
                             float* __restrict__ WT) {
    __shared__ float tile[32][33];
    const int g = blockIdx.z;
    const float* W = (g == 0) ? Wf : (g == 1) ? Wi : (g == 2) ? Wo : Wc;
    const int k0 = blockIdx.x << 5, j0 = blockIdx.y << 5;
    const int tx = threadIdx.x, ty = threadIdx.y;
#pragma unroll
    for (int i = 0; i < 32; i += 8)
        tile[ty + i][tx] = W[(size_t)(EMB + k0 + ty + i) * HID + j0 + tx];
    __syncthreads();
#pragma unroll
    for (int i = 0; i < 32; i += 8)
        WT[(((size_t)g * HID + j0 + ty + i) << 11) + k0 + tx] = tile[tx][ty + i];
}

// A3: init 2-slot mailbox. Slot 0 = h0 with tag 0; slot 1 poisoned with tag
// 0xFFFFFFFF (never equals any step id 0..4095).
__global__ void a3_init(const float* __restrict__ hidden, u64* __restrict__ hbuf, int ring) {
    int j = blockIdx.x * 256 + threadIdx.x;
    int total = ring << 11;
    if (j < total)
        hbuf[j] = (j < HID) ? (u64)__float_as_uint(hidden[j]) : 0xFFFFFFFF00000000ull;
}

// B: persistent recurrence. 256 WGs x 512 threads, weights register-resident.
// Exchange: tagged u64 (tag<<32|f32) mailbox, 2 slots; writer = one
// wave-coalesced 64B-line store per block per step.
// R13 (THE change): AGENT-SCOPE publish. Evidence: R5's WRITE_SIZE decomposed
// baseline 96MB as hs(32)+out(4)+mailbox-writethrough(64 = 16KB x 4096) ->
// every publish crosses the L2->fabric boundary at SYSTEM scope, whose
// coherence point is MEMORY (host-visible) -> plausibly commits at HBM
// (~900cy, m126), and readers' resolving fetch pays the same. GPU-only
// cross-XCD exchange needs only AGENT scope (coherence point = MALL; m20
// HW-verified cross-XCD). Publish = global_store sc1 (agent, write-through
// past L2 to MALL) + an identical-payload sc0sc1 system store as livelock
// insurance (if an agent store could ever park in the writer's local L2,
// the system copy guarantees eventual visibility; identical bits make
// their mutual order irrelevant). Readers keep proven sc0sc1 MALL-direct
// polls -- memory-side MALL cannot be bypassed, so they see the agent
// commit. R5's scattered per-wave atomics reverted (WRITE 3x, MALL-bank
// serialization, 14ms).
__global__ __launch_bounds__(512, 2) void b_lstm(
    const int* __restrict__ seq, const float* __restrict__ cell,
    const float* __restrict__ P, const float* __restrict__ WT,
    u64* __restrict__ hbuf, float* __restrict__ hs, float* __restrict__ dout,
    int rmask) {
    __shared__ float h_lds[HID];
    __shared__ int seq_lds[T_STEPS];
    __shared__ float h_pub[8];
    // Occupancy pin: 89KB static LDS -> exactly 1 block/CU (proven neutral,
    // kept to hold the packing variable fixed across experiments).
    __shared__ float pad_force[16000];
    const int tid = threadIdx.x;
    const int l = tid & 63;
    const int jl = tid >> 6;
    const int jglob = (blockIdx.x << 3) + jl;

    ((volatile float*)pad_force)[tid] = 0.f;

    for (int q = tid; q < T_STEPS; q += 512) seq_lds[q] = seq[q];

    // per-thread k-ownership: k = q*256 + 4*l + r  (q=0..7, r=0..3)
    float4 wreg[4][8];
#pragma unroll
    for (int g = 0; g < 4; ++g)
#pragma unroll
        for (int q = 0; q < 8; ++q)
            wreg[g][q] = *(const float4*)&WT[(((size_t)g * HID + jglob) << 11) + (q << 8) + (l << 2)];

    float c_reg = cell[jglob];
    float h_last = 0.f;
    __syncthreads();

    for (int s = 0; s < T_STEPS; ++s) {
        // publish step s FIRST (values gathered at the end-barrier of iter
        // s-1; for s=0 they come from a3_init). tid 0..7: one 64B line.
        // Agent store commits at the MALL; system twin = eventual-visibility
        // insurance (identical payload -> order between them irrelevant).
        if (s > 0) {
            if (tid < 8) {
                u64 pv = ((u64)(u32)s << 32) | (u64)__float_as_uint(h_pub[tid]);
                u64* dst = hbuf + ((size_t)(s & rmask) << 11) + (blockIdx.x << 3) + tid;
                asm volatile(
                    "global_store_dwordx2 %0, %1, off sc1\n\t"
                    "global_store_dwordx2 %0, %1, off sc0 sc1"
                    ::"v"(dst), "v"(pv) : "memory");
            } else if (tid < 16) {
                hs[((size_t)(s - 1) << 11) + (blockIdx.x << 3) + (tid - 8)] = h_pub[tid - 8];
            }
        }

        const int ch = seq_lds[s];
        const float4 xg = *(const float4*)(P + ((((size_t)ch << 11) + jglob) << 2));

        // stage h_s (tag==s) into LDS; thread tid owns h[tid+512m], m=0..3.
        // MALL-direct polls (sc0 sc1).
        const u64* src = hbuf + ((size_t)(s & rmask) << 11);
        const u64* p0 = src + tid;
        const u64* p1 = p0 + 512;
        const u64* p2 = p0 + 1024;
        const u64* p3 = p0 + 1536;
        const u32 target = (u32)s;
        for (;;) {
            u64 t0, t1, t2, t3;
            asm volatile(
                "global_load_dwordx2 %0, %4, off sc0 sc1\n\t"
                "global_load_dwordx2 %1, %5, off sc0 sc1\n\t"
                "global_load_dwordx2 %2, %6, off sc0 sc1\n\t"
                "global_load_dwordx2 %3, %7, off sc0 sc1\n\t"
                "s_waitcnt vmcnt(0)"
                : "=&v"(t0), "=&v"(t1), "=&v"(t2), "=&v"(t3)
                : "v"(p0), "v"(p1), "v"(p2), "v"(p3)
                : "memory");
            u32 bad = ((u32)(t0 >> 32) ^ target) | ((u32)(t1 >> 32) ^ target) |
                      ((u32)(t2 >> 32) ^ target) | ((u32)(t3 >> 32) ^ target);
            if (bad == 0) {
                h_lds[tid]        = __uint_as_float((u32)t0);
                h_lds[512 + tid]  = __uint_as_float((u32)t1);
                h_lds[1024 + tid] = __uint_as_float((u32)t2);
                h_lds[1536 + tid] = __uint_as_float((u32)t3);
                break;
            }
        }
        __syncthreads();

        float a0 = 0.f, a1 = 0.f, a2 = 0.f, a3 = 0.f;
#pragma unroll
        for (int q = 0; q < 8; ++q) {
            const float4 hv = *(const float4*)&h_lds[(q << 8) + (l << 2)];
            a0 = fmaf(wreg[0][q].x, hv.x, a0);
            a0 = fmaf(wreg[0][q].y, hv.y, a0);
            a0 = fmaf(wreg[0][q].z, hv.z, a0);
            a0 = fmaf(wreg[0][q].w, hv.w, a0);
            a1 = fmaf(wreg[1][q].x, hv.x, a1);
            a1 = fmaf(wreg[1][q].y, hv.y, a1);
            a1 = fmaf(wreg[1][q].z, hv.z, a1);
            a1 = fmaf(wreg[1][q].w, hv.w, a1);
            a2 = fmaf(wreg[2][q].x, hv.x, a2);
            a2 = fmaf(wreg[2][q].y, hv.y, a2);
            a2 = fmaf(wreg[2][q].z, hv.z, a2);
            a2 = fmaf(wreg[2][q].w, hv.w, a2);
            a3 = fmaf(wreg[3][q].x, hv.x, a3);
            a3 = fmaf(wreg[3][q].y, hv.y, a3);
            a3 = fmaf(wreg[3][q].z, hv.z, a3);
            a3 = fmaf(wreg[3][q].w, hv.w, a3);
        }
        // 4-gate quadrant butterfly: fold ^32 (4 gates), split gates across
        // half-waves, fold ^16, split across quadrants, finish ^8..^1.
        a0 += __shfl_xor(a0, 32, 64);
        a1 += __shfl_xor(a1, 32, 64);
        a2 += __shfl_xor(a2, 32, 64);
        a3 += __shfl_xor(a3, 32, 64);
        float u0 = (l < 32) ? a0 : a2;
        float u1 = (l < 32) ? a1 : a3;
        u0 += __shfl_xor(u0, 16, 64);
        u1 += __shfl_xor(u1, 16, 64);
        float w = ((l & 16) == 0) ? u0 : u1;
        w += __shfl_xor(w, 8, 64);
        w += __shfl_xor(w, 4, 64);
        w += __shfl_xor(w, 2, 64);
        w += __shfl_xor(w, 1, 64);
        const float sf = __shfl(w, 0, 64);   // gate f sum
        const float si = __shfl(w, 16, 64);  // gate i sum
        const float so = __shfl(w, 32, 64);  // gate o sum
        const float sg = __shfl(w, 48, 64);  // gate g sum

        const float pf = sf + xg.x, pi = si + xg.y, po = so + xg.z, pg = sg + xg.w;
        const float f = sigm_f(pf);
        const float ii = sigm_f(pi);
        const float oo = sigm_f(po);
        const float gg = tanh_f(pg);
        c_reg = fmaf(f, c_reg, ii * gg);
        h_last = oo * tanh_f(c_reg);   // identical in every lane (broadcast sums)

        if (l == 0) h_pub[jl] = h_last;   // gather for next iter's publish
        __syncthreads();                  // orders h_pub for the publisher wave
    }
    // final publish of step T (values h_{T-1} trace) + finals
    if (tid < 8) {
        hs[((size_t)(T_STEPS - 1) << 11) + (blockIdx.x << 3) + tid] = h_pub[tid];
    }
    if (l == 0) {
        dout[(size_t)T_STEPS * NCH + jglob] = h_last;          // h_fin
        dout[(size_t)T_STEPS * NCH + HID + jglob] = c_reg;     // c_fin
    }
}

// C: out[t] = hs[t] @ Wout + bout. grid 256 (16 t per block), 256 threads.
__global__ __launch_bounds__(256) void c_out(
    const float* __restrict__ hs, const float* __restrict__ Wout,
    const float* __restrict__ bout, float* __restrict__ out) {
    __shared__ float hsl[16][NCH];
    const int tid = threadIdx.x;
    const int bt = blockIdx.x << 4;
    float acc[16];
#pragma unroll
    for (int q = 0; q < 16; ++q) acc[q] = 0.f;
    for (int kc = 0; kc < 8; ++kc) {
#pragma unroll
        for (int q = 0; q < 16; ++q)
            hsl[q][tid] = hs[(((size_t)(bt + q)) << 11) + (kc << 8) + tid];
        __syncthreads();
        for (int kk = 0; kk < 256; ++kk) {
            float w = Wout[(size_t)((kc << 8) + kk) * NCH + tid];
#pragma unroll
            for (int q = 0; q < 16; ++q) acc[q] = fmaf(hsl[q][kk], w, acc[q]);
        }
        __syncthreads();
    }
    const float bb = bout[tid];
#pragma unroll
    for (int q = 0; q < 16; ++q) out[(size_t)(bt + q) * NCH + tid] = acc[q] + bb;
}

extern "C" void kernel_launch(void* const* d_in, const int* in_sizes, int n_in,
                              void* d_out, int out_size, void* d_ws, size_t ws_size,
                              hipStream_t stream) {
    const int* seq = (const int*)d_in[0];
    const float* hidden = (const float*)d_in[1];
    const float* cell = (const float*)d_in[2];
    const float* emb = (const float*)d_in[3];
    const float* Wf = (const float*)d_in[4];
    const float* bf = (const float*)d_in[5];
    const float* Wi = (const float*)d_in[6];
    const float* bi = (const float*)d_in[7];
    const float* Wo = (const float*)d_in[8];
    const float* bo = (const float*)d_in[9];
    const float* Wc = (const float*)d_in[10];
    const float* bc = (const float*)d_in[11];
    const float* Wout = (const float*)d_in[12];
    const float* bout = (const float*)d_in[13];
    float* out = (float*)d_out;

    // ws layout (floats): hbuf(2 slots x 2048 u64 = 8192 f) | WT(16.78M) |
    // P(2.10M) | hs(8.39M)
    float* wsf = (float*)d_ws;
    u64* hbuf = (u64*)d_ws;
    float* WT = wsf + 8192;
    float* P = WT + (size_t)4 * HID * HID;
    float* hs = P + (size_t)NCH * HID * 4;

    a1_proj<<<128, 256, 0, stream>>>(emb, Wf, bf, Wi, bi, Wo, bo, Wc, bc, P);
    a2_transpose<<<dim3(64, 64, 4), dim3(32, 8), 0, stream>>>(Wf, Wi, Wo, Wc, WT);
    a3_init<<<17, 256, 0, stream>>>(hidden, hbuf, 2);
    b_lstm<<<256, 512, 0, stream>>>(seq, cell, P, WT, hbuf, hs, out, 1);
    c_out<<<256, 256, 0, stream>>>(hs, Wout, bout, out);
}

// Round 8
// 10786.299 us; speedup vs baseline: 1.3371x; 1.1488x over previous
//
#include <hip/hip_runtime.h>
#include <hip/hip_bf16.h>

#define T_STEPS 4096
#define HID 2048
#define EMB 512
#define NCH 256

typedef unsigned long long u64;
typedef unsigned int u32;

__device__ __forceinline__ float sigm_f(float x) {
    x = fminf(fmaxf(x, -30.f), 30.f);
    return 1.f / (1.f + __expf(-x));
}
__device__ __forceinline__ float tanh_f(float x) {
    float ax = fminf(fabsf(x), 15.f);
    float e = __expf(2.f * ax);
    float t = (e - 1.f) / (e + 1.f);
    return copysignf(t, x);
}

// A1: per-char input projection P[c][j][g] = b_g[j] + emb[c]·Wg[0:512][j]
__global__ __launch_bounds__(256) void a1_proj(
    const float* __restrict__ emb,
    const float* __restrict__ Wf, const float* __restrict__ bf,
    const float* __restrict__ Wi, const float* __restrict__ bi,
    const float* __restrict__ Wo, const float* __restrict__ bo,
    const float* __restrict__ Wc, const float* __restrict__ bc,
    float* __restrict__ P) {
    const int g = blockIdx.x & 3;
    const int c0 = (blockIdx.x >> 2) << 3;
    const float* W = (g == 0) ? Wf : (g == 1) ? Wi : (g == 2) ? Wo : Wc;
    const float* b = (g == 0) ? bf : (g == 1) ? bi : (g == 2) ? bo : bc;
    __shared__ float el[8][EMB];
    const int tid = threadIdx.x;
    for (int q = tid; q < 8 * EMB; q += 256)
        el[q >> 9][q & 511] = emb[(size_t)(c0 + (q >> 9)) * EMB + (q & 511)];
    __syncthreads();
    float acc[8][8];
#pragma unroll
    for (int cc = 0; cc < 8; ++cc)
#pragma unroll
        for (int k = 0; k < 8; ++k) acc[cc][k] = 0.f;
    for (int e = 0; e < EMB; ++e) {
        float w8[8];
#pragma unroll
        for (int k = 0; k < 8; ++k) w8[k] = W[(size_t)e * HID + tid + (k << 8)];
#pragma unroll
        for (int cc = 0; cc < 8; ++cc) {
            float xe = el[cc][e];
#pragma unroll
            for (int k = 0; k < 8; ++k) acc[cc][k] = fmaf(xe, w8[k], acc[cc][k]);
        }
    }
    float bb[8];
#pragma unroll
    for (int k = 0; k < 8; ++k) bb[k] = b[tid + (k << 8)];
#pragma unroll
    for (int cc = 0; cc < 8; ++cc)
#pragma unroll
        for (int k = 0; k < 8; ++k)
            P[((((size_t)(c0 + cc) << 11) + tid + (k << 8)) << 2) + g] = acc[cc][k] + bb[k];
}

// A2: transpose recurrent weights -> WT[g][j][k] (k contiguous)
__global__ void a2_transpose(const float* __restrict__ Wf, const float* __restrict__ Wi,
                             const float* __restrict__ Wo, const float* __restrict__ Wc,
                             float* __restrict__ WT) {
    __shared__ float tile[32][33];
    const int g = blockIdx.z;
    const float* W = (g == 0) ? Wf : (g == 1) ? Wi : (g == 2) ? Wo : Wc;
    const int k0 = blockIdx.x << 5, j0 = blockIdx.y << 5;
    const int tx = threadIdx.x, ty = threadIdx.y;
#pragma unroll
    for (int i = 0; i < 32; i += 8)
        tile[ty + i][tx] = W[(size_t)(EMB + k0 + ty + i) * HID + j0 + tx];
    __syncthreads();
#pragma unroll
    for (int i = 0; i < 32; i += 8)
        WT[(((size_t)g * HID + j0 + ty + i) << 11) + k0 + tx] = tile[tx][ty + i];
}

// A3: init 8 replica mailboxes. Each replica: slot0 = h0 with tag 0, slot1
// poisoned with tag 0xFFFFFFFF. Replica stride = 4096 u64 (2 slots x 2048).
__global__ void a3_init(const float* __restrict__ hidden, u64* __restrict__ hbuf) {
    int j = blockIdx.x * 256 + threadIdx.x;
    if (j < 8 * 4096) {
        int within = j & 4095;   // position inside this replica
        hbuf[j] = (within < 2048) ? (u64)__float_as_uint(hidden[within])
                                  : 0xFFFFFFFF00000000ull;
    }
}

// B: persistent recurrence. 256 WGs x 512 threads, weights register-resident.
// Exchange: tagged u64 (tag<<32|f32) mailbox.
// R15: PER-XCD REPLICA MAILBOXES (fix of R14's hang). Theory: every latency
// probe (flags/scope/ring/atomics) was null because they all shared the real
// serializer -- every poll round hits the SAME 256 lines with ~2048
// concurrent reads each (8 u64-readers/line x 256 blocks); if the MALL
// serves same-line reads from one bank queue without broadcast-merge, that
// queue IS the ~5000cy wait, invariant to all per-load semantics. Replicas
// spread simultaneous readers across 8x distinct lines (2048 -> 256
// readers/line). Writers: one instruction (tid<64) stores the block's 64B
// line to all 8 replicas (8 coalesced line transactions, fire-and-forget).
// Readers: poll ONLY their own XCD's replica (s_getreg HW_REG_XCC_ID, m09).
// R14's fatal flaw fixed: polls are sc0 sc1 MALL-DIRECT (proven-visible in
// R3/R5/R6 -- write-through data cannot be missed, no stale-L2 livelock;
// R14's sc0-only spin could wait forever on a never-invalidated L2 line,
// consistent with R2's no-sharer-directory finding).
__global__ __launch_bounds__(512, 2) void b_lstm(
    const int* __restrict__ seq, const float* __restrict__ cell,
    const float* __restrict__ P, const float* __restrict__ WT,
    u64* __restrict__ hbuf, float* __restrict__ hs, float* __restrict__ dout) {
    __shared__ float h_lds[HID];
    __shared__ int seq_lds[T_STEPS];
    __shared__ float h_pub[8];
    // Occupancy pin: 89KB static LDS -> exactly 1 block/CU (proven neutral,
    // kept to hold the packing variable fixed across experiments).
    __shared__ float pad_force[16000];
    const int tid = threadIdx.x;
    const int l = tid & 63;
    const int jl = tid >> 6;
    const int jglob = (blockIdx.x << 3) + jl;

    ((volatile float*)pad_force)[tid] = 0.f;

    // which XCD is this block on? (wave-uniform; any value 0..7 is CORRECT,
    // XCC_ID only buys line-disjointness across XCDs)
    u32 xcc;
    asm("s_getreg_b32 %0, hwreg(HW_REG_XCC_ID)" : "=s"(xcc));
    xcc &= 7;

    for (int q = tid; q < T_STEPS; q += 512) seq_lds[q] = seq[q];

    // per-thread k-ownership: k = q*256 + 4*l + r  (q=0..7, r=0..3)
    float4 wreg[4][8];
#pragma unroll
    for (int g = 0; g < 4; ++g)
#pragma unroll
        for (int q = 0; q < 8; ++q)
            wreg[g][q] = *(const float4*)&WT[(((size_t)g * HID + jglob) << 11) + (q << 8) + (l << 2)];

    float c_reg = cell[jglob];
    float h_last = 0.f;
    __syncthreads();

    for (int s = 0; s < T_STEPS; ++s) {
        // publish step s FIRST (values gathered at the end-barrier of iter
        // s-1; for s=0 they come from a3_init). Wave 0, lanes 0..63: lane
        // tid writes u64 (tid&7) of this block's line in replica (tid>>3)
        // -> 8 coalesced 64B-line transactions from ONE instruction,
        // system-scope write-through to the MALL.
        if (s > 0) {
            if (tid < 64) {
                u64 pv = ((u64)(u32)s << 32) | (u64)__float_as_uint(h_pub[tid & 7]);
                u64* dst = hbuf + ((size_t)(tid >> 3) << 12) + ((size_t)(s & 1) << 11)
                         + (blockIdx.x << 3) + (tid & 7);
                __hip_atomic_store(dst, pv, __ATOMIC_RELAXED, __HIP_MEMORY_SCOPE_SYSTEM);
            } else if (tid < 72) {
                hs[((size_t)(s - 1) << 11) + (blockIdx.x << 3) + (tid - 64)] = h_pub[tid - 64];
            }
        }

        const int ch = seq_lds[s];
        const float4 xg = *(const float4*)(P + ((((size_t)ch << 11) + jglob) << 2));

        // stage h_s (tag==s) into LDS from OUR replica; thread tid owns
        // h[tid+512m], m=0..3. sc0 sc1 = MALL-direct (guaranteed progress).
        const u64* src = hbuf + ((size_t)xcc << 12) + ((size_t)(s & 1) << 11);
        const u64* p0 = src + tid;
        const u64* p1 = p0 + 512;
        const u64* p2 = p0 + 1024;
        const u64* p3 = p0 + 1536;
        const u32 target = (u32)s;
        for (;;) {
            u64 t0, t1, t2, t3;
            asm volatile(
                "global_load_dwordx2 %0, %4, off sc0 sc1\n\t"
                "global_load_dwordx2 %1, %5, off sc0 sc1\n\t"
                "global_load_dwordx2 %2, %6, off sc0 sc1\n\t"
                "global_load_dwordx2 %3, %7, off sc0 sc1\n\t"
                "s_waitcnt vmcnt(0)"
                : "=&v"(t0), "=&v"(t1), "=&v"(t2), "=&v"(t3)
                : "v"(p0), "v"(p1), "v"(p2), "v"(p3)
                : "memory");
            u32 bad = ((u32)(t0 >> 32) ^ target) | ((u32)(t1 >> 32) ^ target) |
                      ((u32)(t2 >> 32) ^ target) | ((u32)(t3 >> 32) ^ target);
            if (bad == 0) {
                h_lds[tid]        = __uint_as_float((u32)t0);
                h_lds[512 + tid]  = __uint_as_float((u32)t1);
                h_lds[1024 + tid] = __uint_as_float((u32)t2);
                h_lds[1536 + tid] = __uint_as_float((u32)t3);
                break;
            }
        }
        __syncthreads();

        float a0 = 0.f, a1 = 0.f, a2 = 0.f, a3 = 0.f;
#pragma unroll
        for (int q = 0; q < 8; ++q) {
            const float4 hv = *(const float4*)&h_lds[(q << 8) + (l << 2)];
            a0 = fmaf(wreg[0][q].x, hv.x, a0);
            a0 = fmaf(wreg[0][q].y, hv.y, a0);
            a0 = fmaf(wreg[0][q].z, hv.z, a0);
            a0 = fmaf(wreg[0][q].w, hv.w, a0);
            a1 = fmaf(wreg[1][q].x, hv.x, a1);
            a1 = fmaf(wreg[1][q].y, hv.y, a1);
            a1 = fmaf(wreg[1][q].z, hv.z, a1);
            a1 = fmaf(wreg[1][q].w, hv.w, a1);
            a2 = fmaf(wreg[2][q].x, hv.x, a2);
            a2 = fmaf(wreg[2][q].y, hv.y, a2);
            a2 = fmaf(wreg[2][q].z, hv.z, a2);
            a2 = fmaf(wreg[2][q].w, hv.w, a2);
            a3 = fmaf(wreg[3][q].x, hv.x, a3);
            a3 = fmaf(wreg[3][q].y, hv.y, a3);
            a3 = fmaf(wreg[3][q].z, hv.z, a3);
            a3 = fmaf(wreg[3][q].w, hv.w, a3);
        }
        // 4-gate quadrant butterfly: fold ^32 (4 gates), split gates across
        // half-waves, fold ^16, split across quadrants, finish ^8..^1.
        a0 += __shfl_xor(a0, 32, 64);
        a1 += __shfl_xor(a1, 32, 64);
        a2 += __shfl_xor(a2, 32, 64);
        a3 += __shfl_xor(a3, 32, 64);
        float u0 = (l < 32) ? a0 : a2;
        float u1 = (l < 32) ? a1 : a3;
        u0 += __shfl_xor(u0, 16, 64);
        u1 += __shfl_xor(u1, 16, 64);
        float w = ((l & 16) == 0) ? u0 : u1;
        w += __shfl_xor(w, 8, 64);
        w += __shfl_xor(w, 4, 64);
        w += __shfl_xor(w, 2, 64);
        w += __shfl_xor(w, 1, 64);
        const float sf = __shfl(w, 0, 64);   // gate f sum
        const float si = __shfl(w, 16, 64);  // gate i sum
        const float so = __shfl(w, 32, 64);  // gate o sum
        const float sg = __shfl(w, 48, 64);  // gate g sum

        const float pf = sf + xg.x, pi = si + xg.y, po = so + xg.z, pg = sg + xg.w;
        const float f = sigm_f(pf);
        const float ii = sigm_f(pi);
        const float oo = sigm_f(po);
        const float gg = tanh_f(pg);
        c_reg = fmaf(f, c_reg, ii * gg);
        h_last = oo * tanh_f(c_reg);   // identical in every lane (broadcast sums)

        if (l == 0) h_pub[jl] = h_last;   // gather for next iter's publish
        __syncthreads();                  // orders h_pub for the publisher wave
    }
    // final: hs[T-1] trace + finals
    if (tid < 8) {
        hs[((size_t)(T_STEPS - 1) << 11) + (blockIdx.x << 3) + tid] = h_pub[tid];
    }
    if (l == 0) {
        dout[(size_t)T_STEPS * NCH + jglob] = h_last;          // h_fin
        dout[(size_t)T_STEPS * NCH + HID + jglob] = c_reg;     // c_fin
    }
}

// C: out[t] = hs[t] @ Wout + bout. grid 256 (16 t per block), 256 threads.
__global__ __launch_bounds__(256) void c_out(
    const float* __restrict__ hs, const float* __restrict__ Wout,
    const float* __restrict__ bout, float* __restrict__ out) {
    __shared__ float hsl[16][NCH];
    const int tid = threadIdx.x;
    const int bt = blockIdx.x << 4;
    float acc[16];
#pragma unroll
    for (int q = 0; q < 16; ++q) acc[q] = 0.f;
    for (int kc = 0; kc < 8; ++kc) {
#pragma unroll
        for (int q = 0; q < 16; ++q)
            hsl[q][tid] = hs[(((size_t)(bt + q)) << 11) + (kc << 8) + tid];
        __syncthreads();
        for (int kk = 0; kk < 256; ++kk) {
            float w = Wout[(size_t)((kc << 8) + kk) * NCH + tid];
#pragma unroll
            for (int q = 0; q < 16; ++q) acc[q] = fmaf(hsl[q][kk], w, acc[q]);
        }
        __syncthreads();
    }
    const float bb = bout[tid];
#pragma unroll
    for (int q = 0; q < 16; ++q) out[(size_t)(bt + q) * NCH + tid] = acc[q] + bb;
}

extern "C" void kernel_launch(void* const* d_in, const int* in_sizes, int n_in,
                              void* d_out, int out_size, void* d_ws, size_t ws_size,
                              hipStream_t stream) {
    const int* seq = (const int*)d_in[0];
    const float* hidden = (const float*)d_in[1];
    const float* cell = (const float*)d_in[2];
    const float* emb = (const float*)d_in[3];
    const float* Wf = (const float*)d_in[4];
    const float* bf = (const float*)d_in[5];
    const float* Wi = (const float*)d_in[6];
    const float* bi = (const float*)d_in[7];
    const float* Wo = (const float*)d_in[8];
    const float* bo = (const float*)d_in[9];
    const float* Wc = (const float*)d_in[10];
    const float* bc = (const float*)d_in[11];
    const float* Wout = (const float*)d_in[12];
    const float* bout = (const float*)d_in[13];
    float* out = (float*)d_out;

    // ws layout (floats): hbuf(8 replicas x 2 slots x 2048 u64 = 65536 f) |
    // WT(16.78M) | P(2.10M) | hs(8.39M)
    float* wsf = (float*)d_ws;
    u64* hbuf = (u64*)d_ws;
    float* WT = wsf + 65536;
    float* P = WT + (size_t)4 * HID * HID;
    float* hs = P + (size_t)NCH * HID * 4;

    a1_proj<<<128, 256, 0, stream>>>(emb, Wf, bf, Wi, bi, Wo, bo, Wc, bc, P);
    a2_transpose<<<dim3(64, 64, 4), dim3(32, 8), 0, stream>>>(Wf, Wi, Wo, Wc, WT);
    a3_init<<<128, 256, 0, stream>>>(hidden, hbuf);
    b_lstm<<<256, 512, 0, stream>>>(seq, cell, P, WT, hbuf, hs, out);
    c_out<<<256, 256, 0, stream>>>(hs, Wout, bout, out);
}